// Round 6
// baseline (320.136 us; speedup 1.0000x reference)
//
#include <hip/hip_runtime.h>
#include <hip/hip_bf16.h>

// XCAttention: B=8, N=4096, C=768, H=32, D=24
// K0a: x fp32->bf16; K0b: W transposed->bf16;
// K1: qkv GEMM (128x256, BK=32, 2 blocks/CU, 64x64 wave tiles);
// K2: per-(b,h) XCA core with depth-2 register prefetch;
// K3: proj GEMM (same structure), fp32 out.

#define DEVI __device__ __forceinline__

typedef __attribute__((ext_vector_type(8))) short bf16x8;
typedef __attribute__((ext_vector_type(4))) float f32x4;
typedef unsigned int u32;
typedef unsigned short u16;

DEVI u16 f2bf(float f) {  // RNE float->bf16
  union { float f; u32 u; } x; x.f = f;
  u32 r = x.u + 0x7FFFu + ((x.u >> 16) & 1u);
  return (u16)(r >> 16);
}

DEVI void gload_lds16(const void* g, void* l) {
  __builtin_amdgcn_global_load_lds((__attribute__((address_space(1))) void*)g,
                                   (__attribute__((address_space(3))) void*)l, 16, 0, 0);
}

// ---------------- K0a: fp32 -> bf16 convert ----------------
__global__ __launch_bounds__(256) void cvt_kernel(const float* __restrict__ in,
                                                  u16* __restrict__ out, int n8) {
  int i = blockIdx.x * 256 + threadIdx.x;
  if (i >= n8) return;
  long o = (long)i * 8;
  float4 a = *(const float4*)(in + o);
  float4 b = *(const float4*)(in + o + 4);
  uint4 v;
  v.x = f2bf(a.x) | ((u32)f2bf(a.y) << 16);
  v.y = f2bf(a.z) | ((u32)f2bf(a.w) << 16);
  v.z = f2bf(b.x) | ((u32)f2bf(b.y) << 16);
  v.w = f2bf(b.z) | ((u32)f2bf(b.w) << 16);
  *(uint4*)(out + o) = v;
}

// ---------------- K0b: W (K x N fp32) -> Wt (N x K bf16) ----------------
__global__ __launch_bounds__(256) void transpose_cvt(const float* __restrict__ W,
                                                     u16* __restrict__ Wt, int K, int N) {
  __shared__ float tile[32][33];
  int n0 = blockIdx.x * 32, k0 = blockIdx.y * 32;
  int tx = threadIdx.x, ty = threadIdx.y;  // (32,8)
  #pragma unroll
  for (int i = 0; i < 4; ++i)
    tile[ty + 8 * i][tx] = W[(long)(k0 + ty + 8 * i) * N + n0 + tx];
  __syncthreads();
  #pragma unroll
  for (int i = 0; i < 4; ++i)
    Wt[(long)(n0 + ty + 8 * i) * K + k0 + tx] = f2bf(tile[tx][ty + 8 * i]);
}

// ---------------- 128x256 bf16 MFMA GEMM, BK=32, 2 blocks/CU ----------------
// A: M x K row-major bf16. Bt: N x K row-major bf16. C = A@Bt^T + bias.
// 512 thr = 8 waves (2M x 4N), per-wave 64x64 (FLOP/LDS-byte = 32 vs 21 at 64x32),
// BK=32, 2 K-tile dbuf slots. LDS 48KB: A 2x8KB @0, B 2x16KB @16K.
// Rows of 32 bf16 (64B); st_16x32 swizzle byte^=((byte>>9)&1)<<5
// (inverse-swizzled gload source, swizzled ds_read addr; bit9 = row bit3).
// Per K-tile: stage(kt+1) 3 gloads -> other slot; vmcnt(3); barrier;
// 8 ds_read_b128 + 16 MFMA (setprio); barrier.
template<int NT, int BF16_OUT>
__global__ __launch_bounds__(512, 4) void gemm2b_kernel(
    const u16* __restrict__ A, const u16* __restrict__ Bt,
    const float* __restrict__ bias, void* __restrict__ Cout,
    int M, int N) {
  constexpr int K = NT * 32;
  __shared__ __attribute__((aligned(128))) char lds[49152];

  int nbx = N >> 8;
  int nwg = gridDim.x;
  int bid = blockIdx.x;
  bid = (bid & 7) * (nwg >> 3) + (bid >> 3);  // bijective XCD swizzle (nwg%8==0)
  int bx = bid % nbx, by = bid / nbx;

  int t = threadIdx.x;
  int w = t >> 6, l = t & 63;
  int wr = w >> 2, wc = w & 3;
  int l16 = l & 15, l4 = l >> 4;

  // swizzled frag-read byte bases; row&8 == l16&8 (bases are multiples of 16)
  int cbb = (l4 * 16) ^ ((l16 & 8) << 2);
  int pA0 = (wr * 64 + l16) * 64 + cbb;            // + s*8192  + mi*1024
  int pB0 = 16384 + (wc * 64 + l16) * 64 + cbb;    // + s*16384 + n*1024

  // inverse-swizzled stage source offsets
  int pa = t * 16;
  int la = pa ^ (((pa >> 9) & 1) << 5);
  int soffA = (la >> 6) * K + ((la & 63) >> 1);    // A: 8KB, rows 0..127
  int soffB[2];
  #pragma unroll
  for (int j = 0; j < 2; ++j) {
    int p = (j * 512 + t) * 16;                    // B: 16KB, rows 0..255
    int lb = p ^ (((p >> 9) & 1) << 5);
    soffB[j] = (lb >> 6) * K + ((lb & 63) >> 1);
  }

  const u16* Ag = A + (long)by * 128 * K;
  const u16* Bg = Bt + (long)bx * 256 * K;
  int sdst = w * 1024;  // wave-uniform LDS stage dest base

  f32x4 acc[4][4] = {};

  // prologue: stage tile 0 -> slot 0
  gload_lds16(Ag + soffA, lds + sdst);
  #pragma unroll
  for (int j = 0; j < 2; ++j)
    gload_lds16(Bg + soffB[j], lds + 16384 + j * 8192 + sdst);

  for (int kt = 0; kt < NT; ++kt) {
    int s = kt & 1;
    if (kt + 1 < NT) {
      gload_lds16(Ag + soffA + (kt + 1) * 32, lds + (s ^ 1) * 8192 + sdst);
      #pragma unroll
      for (int j = 0; j < 2; ++j)
        gload_lds16(Bg + soffB[j] + (kt + 1) * 32,
                    lds + 16384 + (s ^ 1) * 16384 + j * 8192 + sdst);
      asm volatile("s_waitcnt vmcnt(3)" ::: "memory");  // tile kt landed, kt+1 in flight
    } else {
      asm volatile("s_waitcnt vmcnt(0)" ::: "memory");
    }
    __builtin_amdgcn_sched_barrier(0);
    __builtin_amdgcn_s_barrier();
    __builtin_amdgcn_sched_barrier(0);

    bf16x8 aF[4], bF[4];
    #pragma unroll
    for (int mi = 0; mi < 4; ++mi)
      aF[mi] = *(const bf16x8*)(lds + s * 8192 + mi * 1024 + pA0);
    #pragma unroll
    for (int n = 0; n < 4; ++n)
      bF[n] = *(const bf16x8*)(lds + s * 16384 + n * 1024 + pB0);

    __builtin_amdgcn_s_setprio(1);
    #pragma unroll
    for (int mi = 0; mi < 4; ++mi)
      #pragma unroll
      for (int n = 0; n < 4; ++n)
        acc[mi][n] = __builtin_amdgcn_mfma_f32_16x16x32_bf16(aF[mi], bF[n], acc[mi][n], 0, 0, 0);
    __builtin_amdgcn_s_setprio(0);
    __builtin_amdgcn_s_barrier();
    __builtin_amdgcn_sched_barrier(0);
  }

  // epilogue (non-temporal: outputs are streaming, keep L2 for A/B panels)
  #pragma unroll
  for (int mi = 0; mi < 4; ++mi) {
    int row0 = by * 128 + wr * 64 + mi * 16 + l4 * 4;
    #pragma unroll
    for (int n = 0; n < 4; ++n) {
      int col = bx * 256 + wc * 64 + n * 16 + l16;
      float bv = bias[col];
      #pragma unroll
      for (int j = 0; j < 4; ++j) {
        long idx = (long)(row0 + j) * N + col;
        float v = acc[mi][n][j] + bv;
        if (BF16_OUT) __builtin_nontemporal_store(f2bf(v), (u16*)Cout + idx);
        else          __builtin_nontemporal_store(v, (float*)Cout + idx);
      }
    }
  }
}

// ---------------- K2: per-(b,h) XCA core (depth-2 reg prefetch) ----------------
#define PFQK(nc, rq, rk)                                                       \
  { long cb = (long)(nc) * 294912;                                             \
    _Pragma("unroll") for (int i = 0; i < 6; ++i) {                            \
      rq[i] = *(const u32*)(qbase + cb + offi[i]);                             \
      rk[i] = *(const u32*)(qbase + cb + offi[i] + 768); } }

#define WRQK(rq, rk)                                                           \
  { _Pragma("unroll") for (int i = 0; i < 6; ++i) {                            \
      qt[dv[i] * 2][nv[i]] = (u16)rq[i];                                       \
      qt[dv[i] * 2 + 1][nv[i]] = (u16)(rq[i] >> 16);                           \
      kt[dv[i] * 2][nv[i]] = (u16)rk[i];                                       \
      kt[dv[i] * 2 + 1][nv[i]] = (u16)(rk[i] >> 16); } }

#define GRAM_MFMA                                                              \
  { _Pragma("unroll") for (int ks = 0; ks < 4; ++ks) {                         \
      int koff = ks * 32 + l4 * 8;                                             \
      bf16x8 qa = *(const bf16x8*)&qt[fm * 16 + l16][koff];                    \
      bf16x8 qb = *(const bf16x8*)&qt[fn * 16 + l16][koff];                    \
      bf16x8 ka = *(const bf16x8*)&kt[fm * 16 + l16][koff];                    \
      bf16x8 kb = *(const bf16x8*)&kt[fn * 16 + l16][koff];                    \
      accG = __builtin_amdgcn_mfma_f32_16x16x32_bf16(qa, kb, accG, 0, 0, 0);   \
      accQ = __builtin_amdgcn_mfma_f32_16x16x32_bf16(qa, qb, accQ, 0, 0, 0);   \
      accK = __builtin_amdgcn_mfma_f32_16x16x32_bf16(ka, kb, accK, 0, 0, 0); } }

#define PFV(nc, rv)                                                            \
  { long cb = (long)(nc) * 294912;                                             \
    _Pragma("unroll") for (int i = 0; i < 6; ++i)                              \
      rv[i] = *(const u32*)(vbase + cb + offi[i]); }

#define WRV(rv)                                                                \
  { _Pragma("unroll") for (int i = 0; i < 6; ++i)                              \
      *(u32*)&vl[nv[i]][dv[i] * 2] = rv[i]; }

#define PV_STORE(nc)                                                           \
  { int n0 = (nc) * 128;                                                       \
    f32x4 z = {};                                                              \
    _Pragma("unroll") for (int fnn = 0; fnn < 2; ++fnn) {                      \
      int ncol = w * 32 + fnn * 16 + l16;                                      \
      bf16x8 bv = *(const bf16x8*)&vl[ncol][l4 * 8];                           \
      f32x4 y0 = __builtin_amdgcn_mfma_f32_16x16x32_bf16(af0, bv, z, 0, 0, 0); \
      f32x4 y1 = __builtin_amdgcn_mfma_f32_16x16x32_bf16(af1, bv, z, 0, 0, 0); \
      int gn = n0 + ncol;                                                      \
      _Pragma("unroll") for (int j = 0; j < 4; ++j) {                          \
        int d0 = l4 * 4 + j;                                                   \
        ybase[(long)d0 * 4096 + gn] = f2bf(y0[j]);                             \
        int d1 = 16 + d0;                                                      \
        if (d1 < 24) ybase[(long)d1 * 4096 + gn] = f2bf(y1[j]); } } }

__global__ __launch_bounds__(256) void attn_kernel(const u16* __restrict__ qkv,
                                                   const float* __restrict__ temperature,
                                                   u16* __restrict__ yout) {
  __shared__ u16 qt[32][136];
  __shared__ u16 kt[32][136];
  __shared__ u16 vl[128][40];
  __shared__ u16 attnb[32][40];
  __shared__ float Gs[32][33];
  __shared__ float sq[32];
  __shared__ float sk[32];

  int bid = blockIdx.x;
  int b = bid >> 5, h = bid & 31;
  int t = threadIdx.x;
  int w = t >> 6, l = t & 63;
  int l16 = l & 15, l4 = l >> 4;
  int fm = w >> 1, fn = w & 1;

  for (int i = t; i < 32 * 136; i += 256) { qt[0][i] = 0; kt[0][i] = 0; }
  for (int i = t; i < 128 * 40; i += 256) vl[0][i] = 0;
  for (int i = t; i < 32 * 40; i += 256) attnb[0][i] = 0;

  int nv[6], dv[6], offi[6];
  #pragma unroll
  for (int i = 0; i < 6; ++i) {
    int idx = t + 256 * i;
    nv[i] = idx / 12; dv[i] = idx % 12;
    offi[i] = nv[i] * 2304 + dv[i] * 2;
  }

  f32x4 accG = {}, accQ = {}, accK = {};
  const u16* qbase = qkv + (long)b * 4096 * 2304 + h * 24;
  const u16* vbase = qbase + 1536;

  u32 rqA[6], rkA[6], rqB[6], rkB[6];
  PFQK(0, rqA, rkA);
  PFQK(1, rqB, rkB);
  __syncthreads();  // zero-init visible

  for (int nc = 0; nc < 32; nc += 2) {
    WRQK(rqA, rkA);
    __syncthreads();
    if (nc + 2 < 32) PFQK(nc + 2, rqA, rkA);
    GRAM_MFMA;
    __syncthreads();
    WRQK(rqB, rkB);
    __syncthreads();
    if (nc + 3 < 32) PFQK(nc + 3, rqB, rkB);
    GRAM_MFMA;
    __syncthreads();
  }

  #pragma unroll
  for (int j = 0; j < 4; ++j) Gs[fm * 16 + l4 * 4 + j][fn * 16 + l16] = accG[j];
  if (fm == fn) {
    #pragma unroll
    for (int j = 0; j < 4; ++j)
      if (l4 * 4 + j == l16) { sq[fm * 16 + l16] = accQ[j]; sk[fm * 16 + l16] = accK[j]; }
  }
  __syncthreads();

  if (t < 24) {
    float nq = fmaxf(sqrtf(fmaxf(sq[t], 0.f)), 1e-12f);
    float tmp = temperature[h];
    float p[24]; float mx = -1e30f;
    #pragma unroll
    for (int e = 0; e < 24; ++e) {
      float nk = fmaxf(sqrtf(fmaxf(sk[e], 0.f)), 1e-12f);
      float a = Gs[t][e] / (nq * nk) * tmp;
      p[e] = a; mx = fmaxf(mx, a);
    }
    float s = 0.f;
    #pragma unroll
    for (int e = 0; e < 24; ++e) { p[e] = __expf(p[e] - mx); s += p[e]; }
    float inv = 1.f / s;
    #pragma unroll
    for (int e = 0; e < 24; ++e) attnb[t][e] = f2bf(p[e] * inv);
  }

  u32 rvA[6], rvB[6];
  PFV(0, rvA);
  PFV(1, rvB);
  __syncthreads();

  bf16x8 af0 = *(const bf16x8*)&attnb[l16][l4 * 8];
  bf16x8 af1 = *(const bf16x8*)&attnb[16 + l16][l4 * 8];
  u16* ybase = yout + (long)(h * 8 + b) * 24 * 4096;

  for (int nc = 0; nc < 32; nc += 2) {
    WRV(rvA);
    __syncthreads();
    if (nc + 2 < 32) PFV(nc + 2, rvA);
    PV_STORE(nc);
    __syncthreads();
    WRV(rvB);
    __syncthreads();
    if (nc + 3 < 32) PFV(nc + 3, rvB);
    PV_STORE(nc + 1);
    __syncthreads();
  }
}

extern "C" void kernel_launch(void* const* d_in, const int* in_sizes, int n_in,
                              void* d_out, int out_size, void* d_ws, size_t ws_size,
                              hipStream_t stream) {
  const float* x     = (const float*)d_in[0];
  const float* Wqkv  = (const float*)d_in[1];
  const float* bqkv  = (const float*)d_in[2];
  const float* temp  = (const float*)d_in[3];
  const float* Wproj = (const float*)d_in[4];
  const float* bproj = (const float*)d_in[5];
  float* out = (float*)d_out;

  char* ws = (char*)d_ws;
  u16* xb  = (u16*)(ws);              // 32768x768 bf16
  u16* wqt = (u16*)(ws + 50331648);   // 2304x768  bf16
  u16* wpt = (u16*)(ws + 53870592);   // 768x768   bf16
  u16* qkv = (u16*)(ws + 55050240);   // 32768x2304 bf16
  u16* y   = xb;                      // x_bf16 dead after GEMM1

  cvt_kernel<<<12288, 256, 0, stream>>>(x, xb, 3145728);
  transpose_cvt<<<dim3(72, 24), dim3(32, 8), 0, stream>>>(Wqkv, wqt, 768, 2304);
  transpose_cvt<<<dim3(24, 24), dim3(32, 8), 0, stream>>>(Wproj, wpt, 768, 768);
  gemm2b_kernel<24, 1><<<2304, 512, 0, stream>>>(xb, wqt, bqkv, qkv, 32768, 2304);
  attn_kernel<<<256, 256, 0, stream>>>(qkv, temp, y);
  gemm2b_kernel<24, 0><<<768, 512, 0, stream>>>(y, wpt, bproj, out, 32768, 768);
}

// Round 7
// 309.579 us; speedup vs baseline: 1.0341x; 1.0341x over previous
//
#include <hip/hip_runtime.h>
#include <hip/hip_bf16.h>

// XCAttention: B=8, N=4096, C=768, H=32, D=24
// K0a: x fp32->bf16; K0b: W transposed->bf16;
// K1: qkv GEMM (128x256, BK=32, 3-slot LDS rotation, 2 blocks/CU);
// K2: per-(b,h) XCA core, 256-row chunks, uint4 loads, depth-2 reg prefetch;
// K3: proj GEMM (same structure), fp32 nt out.

#define DEVI __device__ __forceinline__

typedef __attribute__((ext_vector_type(8))) short bf16x8;
typedef __attribute__((ext_vector_type(4))) float f32x4;
typedef unsigned int u32;
typedef unsigned short u16;

DEVI u16 f2bf(float f) {  // RNE float->bf16
  union { float f; u32 u; } x; x.f = f;
  u32 r = x.u + 0x7FFFu + ((x.u >> 16) & 1u);
  return (u16)(r >> 16);
}

DEVI void gload_lds16(const void* g, void* l) {
  __builtin_amdgcn_global_load_lds((__attribute__((address_space(1))) void*)g,
                                   (__attribute__((address_space(3))) void*)l, 16, 0, 0);
}

// ---------------- K0a: fp32 -> bf16 convert ----------------
__global__ __launch_bounds__(256) void cvt_kernel(const float* __restrict__ in,
                                                  u16* __restrict__ out, int n8) {
  int i = blockIdx.x * 256 + threadIdx.x;
  if (i >= n8) return;
  long o = (long)i * 8;
  float4 a = *(const float4*)(in + o);
  float4 b = *(const float4*)(in + o + 4);
  uint4 v;
  v.x = f2bf(a.x) | ((u32)f2bf(a.y) << 16);
  v.y = f2bf(a.z) | ((u32)f2bf(a.w) << 16);
  v.z = f2bf(b.x) | ((u32)f2bf(b.y) << 16);
  v.w = f2bf(b.z) | ((u32)f2bf(b.w) << 16);
  *(uint4*)(out + o) = v;
}

// ---------------- K0b: W (K x N fp32) -> Wt (N x K bf16) ----------------
__global__ __launch_bounds__(256) void transpose_cvt(const float* __restrict__ W,
                                                     u16* __restrict__ Wt, int K, int N) {
  __shared__ float tile[32][33];
  int n0 = blockIdx.x * 32, k0 = blockIdx.y * 32;
  int tx = threadIdx.x, ty = threadIdx.y;  // (32,8)
  #pragma unroll
  for (int i = 0; i < 4; ++i)
    tile[ty + 8 * i][tx] = W[(long)(k0 + ty + 8 * i) * N + n0 + tx];
  __syncthreads();
  #pragma unroll
  for (int i = 0; i < 4; ++i)
    Wt[(long)(n0 + ty + 8 * i) * K + k0 + tx] = f2bf(tile[tx][ty + 8 * i]);
}

// ---------------- 128x256 bf16 MFMA GEMM, BK=32, 3-slot rotation ----------------
// A: M x K row-major bf16. Bt: N x K row-major bf16. C = A@Bt^T + bias.
// 512 thr = 8 waves (2M x 4N), per-wave 64x64, BK=32, 3 K-tile slots (depth-2
// prefetch, vmcnt(6) covers ~2 iters of HBM latency). LDS 72KB: A 3x8KB @0,
// B 3x16KB @24576 -> 2 blocks/CU (144KB of 160).
// Rows of 32 bf16 (64B); st_16x32 swizzle byte^=((byte>>9)&1)<<5
// (inverse-swizzled gload source, swizzled ds_read addr; bit9 = row bit3).
#define STAGE_T(ktile, slot)                                                   \
  { gload_lds16(Ag + soffA + (ktile) * 32, lds + (slot) * 8192 + sdst);        \
    _Pragma("unroll") for (int j_ = 0; j_ < 2; ++j_)                           \
      gload_lds16(Bg + soffB[j_] + (ktile) * 32,                               \
                  lds + 24576 + (slot) * 16384 + j_ * 8192 + sdst); }

template<int NT, int BF16_OUT>
__global__ __launch_bounds__(512, 4) void gemm2b_kernel(
    const u16* __restrict__ A, const u16* __restrict__ Bt,
    const float* __restrict__ bias, void* __restrict__ Cout,
    int M, int N) {
  constexpr int K = NT * 32;
  __shared__ __attribute__((aligned(128))) char lds[73728];

  int nbx = N >> 8;
  int nwg = gridDim.x;
  int bid = blockIdx.x;
  bid = (bid & 7) * (nwg >> 3) + (bid >> 3);  // bijective XCD swizzle (nwg%8==0)
  int bx = bid % nbx, by = bid / nbx;

  int t = threadIdx.x;
  int w = t >> 6, l = t & 63;
  int wr = w >> 2, wc = w & 3;
  int l16 = l & 15, l4 = l >> 4;

  // swizzled frag-read byte bases; row&8 == l16&8 (other row terms are x16 even)
  int cbb = (l4 * 16) ^ ((l16 & 8) << 2);
  int pA0 = (wr * 64 + l16) * 64 + cbb;            // + slot*8192  + mi*1024
  int pB0 = (wc * 64 + l16) * 64 + cbb;            // + 24576 + slot*16384 + n*1024

  // inverse-swizzled stage source offsets
  int pa = t * 16;
  int la = pa ^ (((pa >> 9) & 1) << 5);
  int soffA = (la >> 6) * K + ((la & 63) >> 1);    // A: 8KB, rows 0..127
  int soffB[2];
  #pragma unroll
  for (int j = 0; j < 2; ++j) {
    int p = (j * 512 + t) * 16;                    // B: 16KB, rows 0..255
    int lb = p ^ (((p >> 9) & 1) << 5);
    soffB[j] = (lb >> 6) * K + ((lb & 63) >> 1);
  }

  const u16* Ag = A + (long)by * 128 * K;
  const u16* Bg = Bt + (long)bx * 256 * K;
  int sdst = w * 1024;  // wave-uniform LDS stage dest base

  f32x4 acc[4][4] = {};

  // prologue: stage tiles 0,1 -> slots 0,1
  STAGE_T(0, 0);
  STAGE_T(1, 1);

  #pragma unroll
  for (int kt = 0; kt < NT; ++kt) {
    int rs = kt % 3;
    if (kt + 2 < NT) {
      STAGE_T(kt + 2, (kt + 2) % 3);
      asm volatile("s_waitcnt vmcnt(6)" ::: "memory");  // tile kt landed; kt+1,kt+2 in flight
    } else if (kt + 2 == NT) {
      asm volatile("s_waitcnt vmcnt(3)" ::: "memory");
    } else {
      asm volatile("s_waitcnt vmcnt(0)" ::: "memory");
    }
    __builtin_amdgcn_sched_barrier(0);
    __builtin_amdgcn_s_barrier();
    __builtin_amdgcn_sched_barrier(0);

    bf16x8 aF[4], bF[4];
    #pragma unroll
    for (int mi = 0; mi < 4; ++mi)
      aF[mi] = *(const bf16x8*)(lds + rs * 8192 + mi * 1024 + pA0);
    #pragma unroll
    for (int n = 0; n < 4; ++n)
      bF[n] = *(const bf16x8*)(lds + 24576 + rs * 16384 + n * 1024 + pB0);

    __builtin_amdgcn_s_setprio(1);
    #pragma unroll
    for (int mi = 0; mi < 4; ++mi)
      #pragma unroll
      for (int n = 0; n < 4; ++n)
        acc[mi][n] = __builtin_amdgcn_mfma_f32_16x16x32_bf16(aF[mi], bF[n], acc[mi][n], 0, 0, 0);
    __builtin_amdgcn_s_setprio(0);
    __builtin_amdgcn_s_barrier();
    __builtin_amdgcn_sched_barrier(0);
  }

  // epilogue: bf16 -> plain stores (L2 write-combining; half-line segments);
  // fp32 -> nt stores (full 64B lines, keep L2 clean)
  #pragma unroll
  for (int mi = 0; mi < 4; ++mi) {
    int row0 = by * 128 + wr * 64 + mi * 16 + l4 * 4;
    #pragma unroll
    for (int n = 0; n < 4; ++n) {
      int col = bx * 256 + wc * 64 + n * 16 + l16;
      float bv = bias[col];
      #pragma unroll
      for (int j = 0; j < 4; ++j) {
        long idx = (long)(row0 + j) * N + col;
        float v = acc[mi][n][j] + bv;
        if (BF16_OUT) ((u16*)Cout)[idx] = f2bf(v);
        else          __builtin_nontemporal_store(v, (float*)Cout + idx);
      }
    }
  }
}

// ---------------- K2: per-(b,h) XCA core ----------------
// 256-row chunks; per row q/k/v = 24 u16 = 3 uint4 segments. (row,seg) pairs:
// 256*3 = 768 = 3 per thread. Depth-2 register prefetch, single LDS buffer.
#define PFQK(nc, rq, rk)                                                       \
  { long cb = (long)(nc) * 589824;                                             \
    _Pragma("unroll") for (int i = 0; i < 3; ++i) {                            \
      rq[i] = *(const uint4*)(qbase + cb + offI[i]);                           \
      rk[i] = *(const uint4*)(kbase + cb + offI[i]); } }

#define WRQK(rq, rk)                                                           \
  { _Pragma("unroll") for (int i = 0; i < 3; ++i) {                            \
      const u32* pq = (const u32*)&rq[i];                                      \
      const u32* pk = (const u32*)&rk[i];                                      \
      _Pragma("unroll") for (int j = 0; j < 4; ++j) {                          \
        int d = sI[i] * 8 + 2 * j;                                             \
        qt[d][nI[i]] = (u16)pq[j]; qt[d + 1][nI[i]] = (u16)(pq[j] >> 16);      \
        kt[d][nI[i]] = (u16)pk[j]; kt[d + 1][nI[i]] = (u16)(pk[j] >> 16); } } }

#define GRAM8                                                                  \
  { _Pragma("unroll") for (int ks = 0; ks < 8; ++ks) {                         \
      int koff = ks * 32 + l4 * 8;                                             \
      bf16x8 qa = *(const bf16x8*)&qt[fm * 16 + l16][koff];                    \
      bf16x8 qb = *(const bf16x8*)&qt[fn * 16 + l16][koff];                    \
      bf16x8 ka = *(const bf16x8*)&kt[fm * 16 + l16][koff];                    \
      bf16x8 kb = *(const bf16x8*)&kt[fn * 16 + l16][koff];                    \
      accG = __builtin_amdgcn_mfma_f32_16x16x32_bf16(qa, kb, accG, 0, 0, 0);   \
      accQ = __builtin_amdgcn_mfma_f32_16x16x32_bf16(qa, qb, accQ, 0, 0, 0);   \
      accK = __builtin_amdgcn_mfma_f32_16x16x32_bf16(ka, kb, accK, 0, 0, 0); } }

#define PFV(nc, rv)                                                            \
  { long cb = (long)(nc) * 589824;                                             \
    _Pragma("unroll") for (int i = 0; i < 3; ++i)                              \
      rv[i] = *(const uint4*)(vbase + cb + offI[i]); }

#define WRV(rv)                                                                \
  { _Pragma("unroll") for (int i = 0; i < 3; ++i)                              \
      *(uint4*)&vl[nI[i]][sI[i] * 8] = rv[i]; }

#define PV_STORE(nc)                                                           \
  { int n0 = (nc) * 256;                                                       \
    f32x4 z = {};                                                              \
    _Pragma("unroll") for (int fnn = 0; fnn < 4; ++fnn) {                      \
      int ncol = w * 64 + fnn * 16 + l16;                                      \
      bf16x8 bv = *(const bf16x8*)&vl[ncol][l4 * 8];                           \
      f32x4 y0 = __builtin_amdgcn_mfma_f32_16x16x32_bf16(af0, bv, z, 0, 0, 0); \
      f32x4 y1 = __builtin_amdgcn_mfma_f32_16x16x32_bf16(af1, bv, z, 0, 0, 0); \
      int gn = n0 + ncol;                                                      \
      _Pragma("unroll") for (int j = 0; j < 4; ++j) {                          \
        int d0 = l4 * 4 + j;                                                   \
        ybase[(long)d0 * 4096 + gn] = f2bf(y0[j]);                             \
        int d1 = 16 + d0;                                                      \
        if (d1 < 24) ybase[(long)d1 * 4096 + gn] = f2bf(y1[j]); } } }

__global__ __launch_bounds__(256) void attn_kernel(const u16* __restrict__ qkv,
                                                   const float* __restrict__ temperature,
                                                   u16* __restrict__ yout) {
  __shared__ u16 qt[32][272];    // [d][n] padded; conflict-free frag reads
  __shared__ u16 kt[32][272];
  __shared__ u16 vl[256][40];    // [n][e] natural v chunk (cols 24..39 zero)
  __shared__ u16 attnb[32][40];
  __shared__ float Gs[32][33];
  __shared__ float sq[32];
  __shared__ float sk[32];

  int bid = blockIdx.x;
  int b = bid >> 5, h = bid & 31;
  int t = threadIdx.x;
  int w = t >> 6, l = t & 63;
  int l16 = l & 15, l4 = l >> 4;
  int fm = w >> 1, fn = w & 1;

  for (int i = t; i < 32 * 272; i += 256) { qt[0][i] = 0; kt[0][i] = 0; }
  for (int i = t; i < 256 * 40; i += 256) vl[0][i] = 0;
  for (int i = t; i < 32 * 40; i += 256) attnb[0][i] = 0;

  int nI[3], sI[3], offI[3];
  #pragma unroll
  for (int i = 0; i < 3; ++i) {
    int idx = t + 256 * i;
    nI[i] = idx / 3; sI[i] = idx % 3;
    offI[i] = nI[i] * 2304 + sI[i] * 8;
  }

  f32x4 accG = {}, accQ = {}, accK = {};
  const u16* qbase = qkv + (long)b * 4096 * 2304 + h * 24;
  const u16* kbase = qbase + 768;
  const u16* vbase = qbase + 1536;

  uint4 rqA[3], rkA[3], rqB[3], rkB[3];
  PFQK(0, rqA, rkA);
  PFQK(1, rqB, rkB);
  __syncthreads();  // zero-init visible

  for (int nc = 0; nc < 16; nc += 2) {
    WRQK(rqA, rkA);
    __syncthreads();
    if (nc + 2 < 16) PFQK(nc + 2, rqA, rkA);
    GRAM8;
    __syncthreads();
    WRQK(rqB, rkB);
    __syncthreads();
    if (nc + 3 < 16) PFQK(nc + 3, rqB, rkB);
    GRAM8;
    __syncthreads();
  }

  #pragma unroll
  for (int j = 0; j < 4; ++j) Gs[fm * 16 + l4 * 4 + j][fn * 16 + l16] = accG[j];
  if (fm == fn) {
    #pragma unroll
    for (int j = 0; j < 4; ++j)
      if (l4 * 4 + j == l16) { sq[fm * 16 + l16] = accQ[j]; sk[fm * 16 + l16] = accK[j]; }
  }
  __syncthreads();

  if (t < 24) {
    float nq = fmaxf(sqrtf(fmaxf(sq[t], 0.f)), 1e-12f);
    float tmp = temperature[h];
    float p[24]; float mx = -1e30f;
    #pragma unroll
    for (int e = 0; e < 24; ++e) {
      float nk = fmaxf(sqrtf(fmaxf(sk[e], 0.f)), 1e-12f);
      float a = Gs[t][e] / (nq * nk) * tmp;
      p[e] = a; mx = fmaxf(mx, a);
    }
    float s = 0.f;
    #pragma unroll
    for (int e = 0; e < 24; ++e) { p[e] = __expf(p[e] - mx); s += p[e]; }
    float inv = 1.f / s;
    #pragma unroll
    for (int e = 0; e < 24; ++e) attnb[t][e] = f2bf(p[e] * inv);
  }

  uint4 rvA[3], rvB[3];
  PFV(0, rvA);
  PFV(1, rvB);
  __syncthreads();

  bf16x8 af0 = *(const bf16x8*)&attnb[l16][l4 * 8];
  bf16x8 af1 = *(const bf16x8*)&attnb[16 + l16][l4 * 8];
  u16* ybase = yout + (long)(h * 8 + b) * 24 * 4096;

  for (int nc = 0; nc < 16; nc += 2) {
    WRV(rvA);
    __syncthreads();
    if (nc + 2 < 16) PFV(nc + 2, rvA);
    PV_STORE(nc);
    __syncthreads();
    WRV(rvB);
    __syncthreads();
    if (nc + 3 < 16) PFV(nc + 3, rvB);
    PV_STORE(nc + 1);
    __syncthreads();
  }
}

extern "C" void kernel_launch(void* const* d_in, const int* in_sizes, int n_in,
                              void* d_out, int out_size, void* d_ws, size_t ws_size,
                              hipStream_t stream) {
  const float* x     = (const float*)d_in[0];
  const float* Wqkv  = (const float*)d_in[1];
  const float* bqkv  = (const float*)d_in[2];
  const float* temp  = (const float*)d_in[3];
  const float* Wproj = (const float*)d_in[4];
  const float* bproj = (const float*)d_in[5];
  float* out = (float*)d_out;

  char* ws = (char*)d_ws;
  u16* xb  = (u16*)(ws);              // 32768x768 bf16
  u16* wqt = (u16*)(ws + 50331648);   // 2304x768  bf16
  u16* wpt = (u16*)(ws + 53870592);   // 768x768   bf16
  u16* qkv = (u16*)(ws + 55050240);   // 32768x2304 bf16
  u16* y   = xb;                      // x_bf16 dead after GEMM1

  cvt_kernel<<<12288, 256, 0, stream>>>(x, xb, 3145728);
  transpose_cvt<<<dim3(72, 24), dim3(32, 8), 0, stream>>>(Wqkv, wqt, 768, 2304);
  transpose_cvt<<<dim3(24, 24), dim3(32, 8), 0, stream>>>(Wproj, wpt, 768, 768);
  gemm2b_kernel<24, 1><<<2304, 512, 0, stream>>>(xb, wqt, bqkv, qkv, 32768, 2304);
  attn_kernel<<<256, 256, 0, stream>>>(qkv, temp, y);
  gemm2b_kernel<24, 0><<<768, 512, 0, stream>>>(y, wpt, bproj, out, 32768, 768);
}